// Round 16
// baseline (115.356 us; speedup 1.0000x reference)
//
#include <hip/hip_runtime.h>

// ParallelHybridScan: chunked linear scan as per-chunk MFMA matmuls.
// B=4 L=2048 H=16 D=64. Chunk T=64 -> C=32. BH=64.
// q~[t,k]=k*exp(-bd*cs[t,k]); k~[t,k]=Bs_t*k*exp(+bd*cs[t,k]); aT=exp(-bd*cs[63,k])
// Phase1 (MFMA): Q_c = diag(aT)*(K~^T V) [bf16]; P_c = aT [fp32]
// Phase2: S_{c+1} = P_c*S_c + Q_c (fp32 state, bf16 I/O; overwrites Q with start states)
// Phase3 (MFMA): G = masked(q~ k~^T); O = G V + q~ S0; out = r*(O+tf*k*v)*g
//
// R16 vs R15: phase3 B2/B5 become RAW barriers (s_waitcnt lgkmcnt(0) +
// s_barrier, NO vmcnt drain — LDS correctness only needs lgkm) so the r/g
// loads issued at end of staging stay in flight across the whole MFMA region
// (~3-4k cycles) and are vmcnt-waited only at the epilogue use. This is the
// minimal T4 (counted-vmcnt) form. R12's spill root cause fixed via
// amdgpu_waves_per_eu(4,4): launch_bounds' 2nd arg is a MINIMUM — the
// allocator was voluntarily targeting 5 waves/EU (96-reg budget) and
// spilling; pinning to exactly 4 gives the full 128-reg budget.

#define B_SZ 4
#define L_SZ 2048
#define H_SZ 16
#define D_SZ 64
#define T_CH 64
#define C_CH (L_SZ / T_CH)   // 32
#define BH (B_SZ * H_SZ)     // 64
#define STRIDE_T (H_SZ * D_SZ)

typedef short short8 __attribute__((ext_vector_type(8)));
typedef float f32x4 __attribute__((ext_vector_type(4)));

// bf16 tile ushort[64][64]; 16B-block XOR swizzle; conflict-free for short8
// row reads (A/B frags) and min-cycle for scalar column writes (measured 0).
#define SWZ(row, col) (((row) << 6) + ((col) ^ (((row) & 7) << 3)))

// LDS-only barrier: ds ops drained + barrier, global loads stay in flight.
#define RAW_BARRIER() asm volatile("s_waitcnt lgkmcnt(0)\n\ts_barrier" ::: "memory")

__device__ __forceinline__ ushort f2bf(float x) {
    unsigned u = __float_as_uint(x);
    u += 0x7FFFu + ((u >> 16) & 1u);   // round-to-nearest-even
    return (ushort)(u >> 16);
}
__device__ __forceinline__ float bf2f(ushort x) {
    return __uint_as_float(((unsigned)x) << 16);
}

__global__ __launch_bounds__(256) void bs_kernel(const float* __restrict__ Bvec,
                                                 float* __restrict__ Bs) {
    int wid = (blockIdx.x * 256 + threadIdx.x) >> 6;
    int lane = threadIdx.x & 63;
    if (wid >= B_SZ * L_SZ) return;
    float s = Bvec[wid * D_SZ + lane];
    #pragma unroll
    for (int m = 32; m >= 1; m >>= 1) s += __shfl_xor(s, m, 64);
    if (lane == 0) Bs[wid] = s * (1.0f / 64.0f);
}

__global__ __launch_bounds__(256, 6) void phase1_mfma(
    const float* __restrict__ kq, const float* __restrict__ vq,
    const float* __restrict__ dq, const float* __restrict__ Bs,
    const float* __restrict__ bd, float* __restrict__ P,
    ushort* __restrict__ Qbf)
{
    int c = blockIdx.x, bh = blockIdx.y;
    int b = bh >> 4, h = bh & 15;
    int tid = threadIdx.x;
    __shared__ __align__(16) ushort tKT[4096];  // K~^T [k][tau]
    __shared__ __align__(16) ushort tVT[4096];  // V^T  [v][tau]
    __shared__ float part[4][D_SZ];
    __shared__ float aTs[D_SZ];

    int t0 = c * T_CH;
    size_t base = ((size_t)(b * L_SZ + t0) * H_SZ + h) * D_SZ;
    int col = tid & 63, qq = tid >> 6;

    float dts[16], kin[16], vin[16];
    #pragma unroll
    for (int j = 0; j < 16; j++) {
        size_t off = base + (size_t)(qq * 16 + j) * STRIDE_T + col;
        dts[j] = dq[off];
        kin[j] = kq[off];
        vin[j] = vq[off];
    }
    float psum = 0.f;
    #pragma unroll
    for (int j = 0; j < 16; j++) psum += dts[j];
    part[qq][col] = psum;
    __syncthreads();                                   // B1

    float cs = 0.f;
    {
        float p0 = part[0][col], p1 = part[1][col], p2 = part[2][col];
        if (qq > 0) cs += p0;
        if (qq > 1) cs += p1;
        if (qq > 2) cs += p2;
    }
    float bdk = bd[h * D_SZ + col];
    short8 klo, khi, vlo, vhi;
    #pragma unroll
    for (int j = 0; j < 16; j++) {
        int t = qq * 16 + j;
        cs += dts[j];
        float bs = Bs[b * L_SZ + t0 + t];
        ushort kt = f2bf(bs * kin[j] * __expf(bdk * cs));
        ushort vt = f2bf(vin[j]);
        if (j < 8) { klo[j] = (short)kt; vlo[j] = (short)vt; }
        else       { khi[j - 8] = (short)kt; vhi[j - 8] = (short)vt; }
    }
    if (qq == 3) aTs[col] = __expf(-bdk * cs);
    *(short8*)&tKT[SWZ(col, qq * 16)]     = klo;
    *(short8*)&tKT[SWZ(col, qq * 16 + 8)] = khi;
    *(short8*)&tVT[SWZ(col, qq * 16)]     = vlo;
    *(short8*)&tVT[SWZ(col, qq * 16 + 8)] = vhi;
    __syncthreads();                                   // B2

    int lane = tid & 63, w = tid >> 6;
    int lg = lane >> 4, lr = lane & 15;
    f32x4 acc[4] = {};
    #pragma unroll
    for (int s = 0; s < 2; s++) {
        short8 a = *(const short8*)&tKT[SWZ(16 * w + lr, 32 * s + lg * 8)];
        #pragma unroll
        for (int j = 0; j < 4; j++) {
            short8 bv = *(const short8*)&tVT[SWZ(16 * j + lr, 32 * s + lg * 8)];
            acc[j] = __builtin_amdgcn_mfma_f32_16x16x32_bf16(a, bv, acc[j], 0, 0, 0);
        }
    }

    size_t qb = (size_t)(bh * C_CH + c) * (D_SZ * D_SZ);
    #pragma unroll
    for (int j = 0; j < 4; j++) {
        #pragma unroll
        for (int reg = 0; reg < 4; reg++) {
            int k = 16 * w + lg * 4 + reg;
            Qbf[qb + k * D_SZ + 16 * j + lr] = f2bf(aTs[k] * acc[j][reg]);
        }
    }
    if (tid < D_SZ)
        P[(size_t)(bh * C_CH + c) * D_SZ + tid] = aTs[tid];
}

// Sequential combine; fp32 state in regs, bf16 Q I/O, fp32 out2. 8 rows/block.
__global__ __launch_bounds__(64) void phase2(const float* __restrict__ P,
                                             ushort* __restrict__ Qrw,
                                             float* __restrict__ out2) {
    int bh = blockIdx.x, kqi = blockIdx.y;
    int lane = threadIdx.x;
    float S[8];
    #pragma unroll
    for (int i = 0; i < 8; i++) S[i] = 0.f;

    size_t pb = (size_t)bh * C_CH * D_SZ + kqi * 8;
    size_t qb = ((size_t)bh * C_CH * D_SZ + kqi * 8) * D_SZ + lane;
    const size_t qstep = (size_t)D_SZ * D_SZ;

    float pc[8]; ushort qc[8];
    #pragma unroll
    for (int i = 0; i < 8; i++) {
        pc[i] = P[pb + i];
        qc[i] = Qrw[qb + (size_t)i * D_SZ];
    }
    for (int c = 0; c < C_CH; c++) {
        float pn[8] = {}; ushort qn[8] = {};
        if (c < C_CH - 1) {
            #pragma unroll
            for (int i = 0; i < 8; i++) {
                pn[i] = P[pb + (size_t)(c + 1) * D_SZ + i];
                qn[i] = Qrw[qb + (size_t)(c + 1) * qstep + (size_t)i * D_SZ];
            }
        }
        #pragma unroll
        for (int i = 0; i < 8; i++) {
            Qrw[qb + (size_t)c * qstep + (size_t)i * D_SZ] = f2bf(S[i]);
            S[i] = fmaf(pc[i], S[i], bf2f(qc[i]));
            pc[i] = pn[i]; qc[i] = qn[i];
        }
    }
    size_t ob = ((size_t)bh * D_SZ + kqi * 8) * D_SZ + lane;
    #pragma unroll
    for (int i = 0; i < 8; i++) out2[ob + (size_t)i * D_SZ] = S[i];
}

__global__ __launch_bounds__(256, 4) __attribute__((amdgpu_waves_per_eu(4, 4)))
void phase3_mfma(
    const float* __restrict__ kq, const float* __restrict__ vq,
    const float* __restrict__ dq, const float* __restrict__ rq,
    const float* __restrict__ gq, const float* __restrict__ Bs,
    const float* __restrict__ bd, const float* __restrict__ tf,
    const ushort* __restrict__ Sb, float* __restrict__ out)
{
    int c = blockIdx.x, bh = blockIdx.y;
    int b = bh >> 4, h = bh & 15;
    int tid = threadIdx.x;
    __shared__ __align__(16) ushort SH[20480];          // 40 KB; 4 blocks/CU (160KB)
    ushort* tQ  = SH;                                   // q~ [t][k]          (A: own-band)
    ushort* tKG = SH + 4096;                            // k~ [tau][k]        (B: cross-wave, write-once)
    ushort* tS0 = SH + 8192;                            // S0^T [v][k]        (B: cross-wave, write-once)
    ushort* tVT = SH + 12288;                           // V^T [v][tau]       (B: cross-wave, write-once)
    ushort* tG  = SH + 16384;                           // G [t][tau]         (wave-local: own-band W+R)
    float*  ACC = (float*)SH;                           // fp32 [64][64], aliases tQ+tKG
    float*  part = (float*)(SH + 16384);                // 1 KB, aliases tG rows 0-7

    int t0 = c * T_CH;
    size_t base = ((size_t)(b * L_SZ + t0) * H_SZ + h) * D_SZ;
    size_t sb = (size_t)(bh * C_CH + c) * (D_SZ * D_SZ);
    int col = tid & 63, qq = tid >> 6;

    // column pass: loads for cumsum + transposed staging
    float dts[16], kin[16], vin[16];
    ushort s0c[16];
    #pragma unroll
    for (int j = 0; j < 16; j++) {
        int t = qq * 16 + j;
        size_t off = base + (size_t)t * STRIDE_T + col;
        dts[j] = dq[off];
        kin[j] = kq[off];
        vin[j] = vq[off];
        s0c[j] = Sb[sb + (size_t)t * D_SZ + col];   // S0[k=t][v=col]
    }
    float psum = 0.f;
    #pragma unroll
    for (int j = 0; j < 16; j++) psum += dts[j];
    part[qq * D_SZ + col] = psum;
    __syncthreads();                                   // B1 (cross-wave: part)

    float cs = 0.f;
    {
        float p0 = part[0 * D_SZ + col], p1 = part[1 * D_SZ + col], p2 = part[2 * D_SZ + col];
        if (qq > 0) cs += p0;
        if (qq > 1) cs += p1;
        if (qq > 2) cs += p2;
    }
    float bdk = bd[h * D_SZ + col];
    float tfv = tf[h * D_SZ + col];
    float bon[16];
    short8 vlo, vhi, slo, shi;
    #pragma unroll
    for (int j = 0; j < 16; j++) {
        int t = qq * 16 + j;
        cs += dts[j];
        float bs = Bs[b * L_SZ + t0 + t];
        tQ[SWZ(t, col)]  = f2bf(kin[j] * __expf(-bdk * cs));   // col write, min-cycle
        tKG[SWZ(t, col)] = f2bf(bs * kin[j] * __expf(bdk * cs));
        ushort vt = f2bf(vin[j]);
        bon[j] = tfv * kin[j] * vin[j];                        // kin/vin die here
        if (j < 8) { vlo[j] = (short)vt; slo[j] = (short)s0c[j]; }
        else       { vhi[j - 8] = (short)vt; shi[j - 8] = (short)s0c[j]; }
    }
    *(short8*)&tVT[SWZ(col, qq * 16)]     = vlo;       // V^T row `col`
    *(short8*)&tVT[SWZ(col, qq * 16 + 8)] = vhi;
    *(short8*)&tS0[SWZ(col, qq * 16)]     = slo;       // S0^T row `col`
    *(short8*)&tS0[SWZ(col, qq * 16 + 8)] = shi;

    // r/g issued HERE; stay in flight across B2 (raw barrier: no vmcnt drain)
    // and the whole MFMA region. vmcnt auto-waited at epilogue use.
    float rin[16], gin[16];
    #pragma unroll
    for (int j = 0; j < 16; j++) {
        size_t off = base + (size_t)(qq * 16 + j) * STRIDE_T + col;
        rin[j] = rq[off];
        gin[j] = gq[off];
    }
    RAW_BARRIER();                                     // B2 (LDS-only)

    int lane = tid & 63, w = tid >> 6;
    int lg = lane >> 4, lr = lane & 15;

    // G = q~ k~^T ; O1 = q~ S0
    f32x4 gacc[4] = {};
    f32x4 acc[4] = {};
    #pragma unroll
    for (int s = 0; s < 2; s++) {
        short8 a = *(const short8*)&tQ[SWZ(16 * w + lr, 32 * s + lg * 8)];
        #pragma unroll
        for (int j = 0; j < 4; j++) {
            short8 bk = *(const short8*)&tKG[SWZ(16 * j + lr, 32 * s + lg * 8)];
            gacc[j] = __builtin_amdgcn_mfma_f32_16x16x32_bf16(a, bk, gacc[j], 0, 0, 0);
            short8 b0 = *(const short8*)&tS0[SWZ(16 * j + lr, 32 * s + lg * 8)];
            acc[j] = __builtin_amdgcn_mfma_f32_16x16x32_bf16(a, b0, acc[j], 0, 0, 0);
        }
    }

    // masked G -> tG (own band; wave-local, lgkm ordering via data deps)
    #pragma unroll
    for (int j = 0; j < 4; j++) {
        #pragma unroll
        for (int reg = 0; reg < 4; reg++) {
            int t = 16 * w + lg * 4 + reg;
            int tau = 16 * j + lr;
            tG[SWZ(t, tau)] = (tau <= t) ? f2bf(gacc[j][reg]) : (ushort)0;
        }
    }

    // O2 += G V
    #pragma unroll
    for (int s = 0; s < 2; s++) {
        short8 a = *(const short8*)&tG[SWZ(16 * w + lr, 32 * s + lg * 8)];
        #pragma unroll
        for (int j = 0; j < 4; j++) {
            short8 bv = *(const short8*)&tVT[SWZ(16 * j + lr, 32 * s + lg * 8)];
            acc[j] = __builtin_amdgcn_mfma_f32_16x16x32_bf16(a, bv, acc[j], 0, 0, 0);
        }
    }
    RAW_BARRIER();                                     // B5 (LDS-only): cross-wave
                                                       // tQ/tKG reads done -> ACC overwrite

    // acc -> fp32 LDS tile (aliases tQ+tKG), 2-way-free swizzle (own band)
    #pragma unroll
    for (int j = 0; j < 4; j++) {
        #pragma unroll
        for (int reg = 0; reg < 4; reg++) {
            int t = 16 * w + lg * 4 + reg;
            int v = 16 * j + lr;
            ACC[t * D_SZ + (v ^ (((t >> 2) & 1) << 4))] = acc[j][reg];
        }
    }

    // coalesced column-pass epilogue (bon/rin/gin in registers)
    #pragma unroll
    for (int j = 0; j < 16; j++) {
        int t = qq * 16 + j;
        size_t off = base + (size_t)t * STRIDE_T + col;
        float a = ACC[t * D_SZ + (col ^ (((t >> 2) & 1) << 4))];
        out[off] = rin[j] * (a + bon[j]) * gin[j];
    }
}

extern "C" void kernel_launch(void* const* d_in, const int* in_sizes, int n_in,
                              void* d_out, int out_size, void* d_ws, size_t ws_size,
                              hipStream_t stream) {
    const float* k    = (const float*)d_in[0];
    const float* v    = (const float*)d_in[1];
    const float* dt   = (const float*)d_in[2];
    const float* Bvec = (const float*)d_in[3];
    // d_in[4] = C_vec (unused by reference)
    const float* r    = (const float*)d_in[5];
    const float* g    = (const float*)d_in[6];
    const float* bd   = (const float*)d_in[7];
    const float* tf   = (const float*)d_in[8];

    float* out  = (float*)d_out;
    float* out2 = out + (size_t)B_SZ * L_SZ * H_SZ * D_SZ;

    float* Bs  = (float*)d_ws;                              // B*L fp32
    float* P   = Bs + B_SZ * L_SZ;                          // BH*C*D fp32
    ushort* Qb = (ushort*)(P + (size_t)BH * C_CH * D_SZ);   // BH*C*D*D bf16 (16.8 MB)

    bs_kernel<<<dim3(B_SZ * L_SZ / 4), 256, 0, stream>>>(Bvec, Bs);
    phase1_mfma<<<dim3(C_CH, BH), 256, 0, stream>>>(k, v, dt, Bs, bd, P, Qb);
    phase2<<<dim3(BH, 8), 64, 0, stream>>>(P, Qb, out2);
    phase3_mfma<<<dim3(C_CH, BH), 256, 0, stream>>>(k, v, dt, r, g, Bs, bd, tf, Qb, out);
}

// Round 17
// 69.094 us; speedup vs baseline: 1.6695x; 1.6695x over previous
//
#include <hip/hip_runtime.h>

// ParallelHybridScan: chunked linear scan as per-chunk MFMA matmuls.
// B=4 L=2048 H=16 D=64. Chunk T=64 -> C=32. BH=64.
// q~[t,k]=k*exp(-bd*cs[t,k]); k~[t,k]=Bs_t*k*exp(+bd*cs[t,k]); aT=exp(-bd*cs[63,k])
// Phase1 (MFMA): Q_c = diag(aT)*(K~^T V) [bf16]; P_c = aT [fp32]
// Phase2: S_{c+1} = P_c*S_c + Q_c (fp32 state, bf16 I/O; overwrites Q with start states)
// Phase3 (MFMA): G = masked(q~ k~^T); O = G V + q~ S0; out = r*(O+tf*k*v)*g
//
// R17: phase3 reverted to R14 (best, 44us; five spill-failures R9/R10/R12/R13/
// R16 prove the allocator pins 64 arch-VGPRs with 32 unified-file accs live —
// r/g must load in the epilogue). NEW: phase2 prefetch 1-deep -> 4-deep
// rotated register buffers (fully-unrolled chunk loop => static slot indices,
// rule #20-safe). P/Q loads are independent across chunks; only S is serial.
// Cuts phase2's exposed HBM latency ~4x.

#define B_SZ 4
#define L_SZ 2048
#define H_SZ 16
#define D_SZ 64
#define T_CH 64
#define C_CH (L_SZ / T_CH)   // 32
#define BH (B_SZ * H_SZ)     // 64
#define STRIDE_T (H_SZ * D_SZ)

typedef short short8 __attribute__((ext_vector_type(8)));
typedef float f32x4 __attribute__((ext_vector_type(4)));

// bf16 tile ushort[64][64]; 16B-block XOR swizzle; conflict-free for short8
// row reads (A/B frags) and min-cycle for scalar column writes (measured 0).
#define SWZ(row, col) (((row) << 6) + ((col) ^ (((row) & 7) << 3)))

__device__ __forceinline__ ushort f2bf(float x) {
    unsigned u = __float_as_uint(x);
    u += 0x7FFFu + ((u >> 16) & 1u);   // round-to-nearest-even
    return (ushort)(u >> 16);
}
__device__ __forceinline__ float bf2f(ushort x) {
    return __uint_as_float(((unsigned)x) << 16);
}

__global__ __launch_bounds__(256) void bs_kernel(const float* __restrict__ Bvec,
                                                 float* __restrict__ Bs) {
    int wid = (blockIdx.x * 256 + threadIdx.x) >> 6;
    int lane = threadIdx.x & 63;
    if (wid >= B_SZ * L_SZ) return;
    float s = Bvec[wid * D_SZ + lane];
    #pragma unroll
    for (int m = 32; m >= 1; m >>= 1) s += __shfl_xor(s, m, 64);
    if (lane == 0) Bs[wid] = s * (1.0f / 64.0f);
}

__global__ __launch_bounds__(256, 6) void phase1_mfma(
    const float* __restrict__ kq, const float* __restrict__ vq,
    const float* __restrict__ dq, const float* __restrict__ Bs,
    const float* __restrict__ bd, float* __restrict__ P,
    ushort* __restrict__ Qbf)
{
    int c = blockIdx.x, bh = blockIdx.y;
    int b = bh >> 4, h = bh & 15;
    int tid = threadIdx.x;
    __shared__ __align__(16) ushort tKT[4096];  // K~^T [k][tau]
    __shared__ __align__(16) ushort tVT[4096];  // V^T  [v][tau]
    __shared__ float part[4][D_SZ];
    __shared__ float aTs[D_SZ];

    int t0 = c * T_CH;
    size_t base = ((size_t)(b * L_SZ + t0) * H_SZ + h) * D_SZ;
    int col = tid & 63, qq = tid >> 6;

    float dts[16], kin[16], vin[16];
    #pragma unroll
    for (int j = 0; j < 16; j++) {
        size_t off = base + (size_t)(qq * 16 + j) * STRIDE_T + col;
        dts[j] = dq[off];
        kin[j] = kq[off];
        vin[j] = vq[off];
    }
    float psum = 0.f;
    #pragma unroll
    for (int j = 0; j < 16; j++) psum += dts[j];
    part[qq][col] = psum;
    __syncthreads();                                   // B1

    float cs = 0.f;
    {
        float p0 = part[0][col], p1 = part[1][col], p2 = part[2][col];
        if (qq > 0) cs += p0;
        if (qq > 1) cs += p1;
        if (qq > 2) cs += p2;
    }
    float bdk = bd[h * D_SZ + col];
    short8 klo, khi, vlo, vhi;
    #pragma unroll
    for (int j = 0; j < 16; j++) {
        int t = qq * 16 + j;
        cs += dts[j];
        float bs = Bs[b * L_SZ + t0 + t];
        ushort kt = f2bf(bs * kin[j] * __expf(bdk * cs));
        ushort vt = f2bf(vin[j]);
        if (j < 8) { klo[j] = (short)kt; vlo[j] = (short)vt; }
        else       { khi[j - 8] = (short)kt; vhi[j - 8] = (short)vt; }
    }
    if (qq == 3) aTs[col] = __expf(-bdk * cs);
    *(short8*)&tKT[SWZ(col, qq * 16)]     = klo;
    *(short8*)&tKT[SWZ(col, qq * 16 + 8)] = khi;
    *(short8*)&tVT[SWZ(col, qq * 16)]     = vlo;
    *(short8*)&tVT[SWZ(col, qq * 16 + 8)] = vhi;
    __syncthreads();                                   // B2

    int lane = tid & 63, w = tid >> 6;
    int lg = lane >> 4, lr = lane & 15;
    f32x4 acc[4] = {};
    #pragma unroll
    for (int s = 0; s < 2; s++) {
        short8 a = *(const short8*)&tKT[SWZ(16 * w + lr, 32 * s + lg * 8)];
        #pragma unroll
        for (int j = 0; j < 4; j++) {
            short8 bv = *(const short8*)&tVT[SWZ(16 * j + lr, 32 * s + lg * 8)];
            acc[j] = __builtin_amdgcn_mfma_f32_16x16x32_bf16(a, bv, acc[j], 0, 0, 0);
        }
    }

    size_t qb = (size_t)(bh * C_CH + c) * (D_SZ * D_SZ);
    #pragma unroll
    for (int j = 0; j < 4; j++) {
        #pragma unroll
        for (int reg = 0; reg < 4; reg++) {
            int k = 16 * w + lg * 4 + reg;
            Qbf[qb + k * D_SZ + 16 * j + lr] = f2bf(aTs[k] * acc[j][reg]);
        }
    }
    if (tid < D_SZ)
        P[(size_t)(bh * C_CH + c) * D_SZ + tid] = aTs[tid];
}

// Sequential combine; fp32 state in regs, bf16 Q I/O, fp32 out2. 8 rows/block.
// 4-deep rotated prefetch: chunk loop fully unrolled -> slot indices static.
__global__ __launch_bounds__(64) void phase2(const float* __restrict__ P,
                                             ushort* __restrict__ Qrw,
                                             float* __restrict__ out2) {
    int bh = blockIdx.x, kqi = blockIdx.y;
    int lane = threadIdx.x;
    float S[8];
    #pragma unroll
    for (int i = 0; i < 8; i++) S[i] = 0.f;

    size_t pb = (size_t)bh * C_CH * D_SZ + kqi * 8;
    size_t qb = ((size_t)bh * C_CH * D_SZ + kqi * 8) * D_SZ + lane;
    const size_t qstep = (size_t)D_SZ * D_SZ;

    float pbuf[4][8];
    ushort qbuf[4][8];
    #pragma unroll
    for (int s = 0; s < 3; s++) {
        #pragma unroll
        for (int i = 0; i < 8; i++) {
            pbuf[s][i] = P[pb + (size_t)s * D_SZ + i];
            qbuf[s][i] = Qrw[qb + (size_t)s * qstep + (size_t)i * D_SZ];
        }
    }
    #pragma unroll
    for (int c = 0; c < C_CH; c++) {
        const int sl = c & 3;          // compile-time after full unroll
        const int pf = (c + 3) & 3;
        if (c + 3 < C_CH) {            // prefetch chunk c+3 into slot pf
            #pragma unroll
            for (int i = 0; i < 8; i++) {
                pbuf[pf][i] = P[pb + (size_t)(c + 3) * D_SZ + i];
                qbuf[pf][i] = Qrw[qb + (size_t)(c + 3) * qstep + (size_t)i * D_SZ];
            }
        }
        #pragma unroll
        for (int i = 0; i < 8; i++) {
            Qrw[qb + (size_t)c * qstep + (size_t)i * D_SZ] = f2bf(S[i]);
            S[i] = fmaf(pbuf[sl][i], S[i], bf2f(qbuf[sl][i]));
        }
    }
    size_t ob = ((size_t)bh * D_SZ + kqi * 8) * D_SZ + lane;
    #pragma unroll
    for (int i = 0; i < 8; i++) out2[ob + (size_t)i * D_SZ] = S[i];
}

__global__ __launch_bounds__(256, 4) void phase3_mfma(
    const float* __restrict__ kq, const float* __restrict__ vq,
    const float* __restrict__ dq, const float* __restrict__ rq,
    const float* __restrict__ gq, const float* __restrict__ Bs,
    const float* __restrict__ bd, const float* __restrict__ tf,
    const ushort* __restrict__ Sb, float* __restrict__ out)
{
    int c = blockIdx.x, bh = blockIdx.y;
    int b = bh >> 4, h = bh & 15;
    int tid = threadIdx.x;
    __shared__ __align__(16) ushort SH[16384];          // 32 KB
    ushort* tQ  = SH;                                   // q~ [t][k]
    ushort* tKG = SH + 4096;                            // k~ [tau][k] -> G [t][tau]
    ushort* tS0 = SH + 8192;                            // S0^T [v][k]
    ushort* tVT = SH + 12288;                           // V^T [v][tau]
    float*  ACC = (float*)SH;                           // fp32 [64][64], aliases tQ+tKG
    float*  part = (float*)SH;                          // 1 KB, aliases tQ rows 0-7
                                                        // (tQ written only after B1b)

    int t0 = c * T_CH;
    size_t base = ((size_t)(b * L_SZ + t0) * H_SZ + h) * D_SZ;
    size_t sb = (size_t)(bh * C_CH + c) * (D_SZ * D_SZ);
    int col = tid & 63, qq = tid >> 6;

    // column pass: loads for cumsum + transposed staging
    float dts[16], kin[16], vin[16];
    ushort s0c[16];
    #pragma unroll
    for (int j = 0; j < 16; j++) {
        int t = qq * 16 + j;
        size_t off = base + (size_t)t * STRIDE_T + col;
        dts[j] = dq[off];
        kin[j] = kq[off];
        vin[j] = vq[off];
        s0c[j] = Sb[sb + (size_t)t * D_SZ + col];   // S0[k=t][v=col]
    }
    float psum = 0.f;
    #pragma unroll
    for (int j = 0; j < 16; j++) psum += dts[j];
    part[qq * D_SZ + col] = psum;
    __syncthreads();                                   // B1

    float cs = 0.f;
    {
        float p0 = part[0 * D_SZ + col], p1 = part[1 * D_SZ + col], p2 = part[2 * D_SZ + col];
        if (qq > 0) cs += p0;
        if (qq > 1) cs += p1;
        if (qq > 2) cs += p2;
    }
    __syncthreads();                                   // B1b: part region free for tQ writes

    float bdk = bd[h * D_SZ + col];
    float tfv = tf[h * D_SZ + col];
    float bon[16];
    short8 vlo, vhi, slo, shi;
    #pragma unroll
    for (int j = 0; j < 16; j++) {
        int t = qq * 16 + j;
        cs += dts[j];
        float bs = Bs[b * L_SZ + t0 + t];
        tQ[SWZ(t, col)]  = f2bf(kin[j] * __expf(-bdk * cs));   // col write, min-cycle
        tKG[SWZ(t, col)] = f2bf(bs * kin[j] * __expf(bdk * cs));
        ushort vt = f2bf(vin[j]);
        bon[j] = tfv * kin[j] * vin[j];                        // kin/vin die here
        if (j < 8) { vlo[j] = (short)vt; slo[j] = (short)s0c[j]; }
        else       { vhi[j - 8] = (short)vt; shi[j - 8] = (short)s0c[j]; }
    }
    *(short8*)&tVT[SWZ(col, qq * 16)]     = vlo;       // V^T row `col`
    *(short8*)&tVT[SWZ(col, qq * 16 + 8)] = vhi;
    *(short8*)&tS0[SWZ(col, qq * 16)]     = slo;       // S0^T row `col`
    *(short8*)&tS0[SWZ(col, qq * 16 + 8)] = shi;
    __syncthreads();                                   // B2

    int lane = tid & 63, w = tid >> 6;
    int lg = lane >> 4, lr = lane & 15;

    // G = q~ k~^T ; O1 = q~ S0
    f32x4 gacc[4] = {};
    f32x4 acc[4] = {};
    #pragma unroll
    for (int s = 0; s < 2; s++) {
        short8 a = *(const short8*)&tQ[SWZ(16 * w + lr, 32 * s + lg * 8)];
        #pragma unroll
        for (int j = 0; j < 4; j++) {
            short8 bk = *(const short8*)&tKG[SWZ(16 * j + lr, 32 * s + lg * 8)];
            gacc[j] = __builtin_amdgcn_mfma_f32_16x16x32_bf16(a, bk, gacc[j], 0, 0, 0);
            short8 b0 = *(const short8*)&tS0[SWZ(16 * j + lr, 32 * s + lg * 8)];
            acc[j] = __builtin_amdgcn_mfma_f32_16x16x32_bf16(a, b0, acc[j], 0, 0, 0);
        }
    }
    __syncthreads();                                   // B3: k~ readers done

    // masked G -> tKG  (C-frag: t = 16w + lg*4 + reg, tau = 16j + lr)
    #pragma unroll
    for (int j = 0; j < 4; j++) {
        #pragma unroll
        for (int reg = 0; reg < 4; reg++) {
            int t = 16 * w + lg * 4 + reg;
            int tau = 16 * j + lr;
            tKG[SWZ(t, tau)] = (tau <= t) ? f2bf(gacc[j][reg]) : (ushort)0;
        }
    }
    __syncthreads();                                   // B4

    // O2 += G V
    #pragma unroll
    for (int s = 0; s < 2; s++) {
        short8 a = *(const short8*)&tKG[SWZ(16 * w + lr, 32 * s + lg * 8)];
        #pragma unroll
        for (int j = 0; j < 4; j++) {
            short8 bv = *(const short8*)&tVT[SWZ(16 * j + lr, 32 * s + lg * 8)];
            acc[j] = __builtin_amdgcn_mfma_f32_16x16x32_bf16(a, bv, acc[j], 0, 0, 0);
        }
    }
    __syncthreads();                                   // B5: all bf16 tiles dead

    // acc -> fp32 LDS tile (aliases tQ+tKG), 2-way-free swizzle
    #pragma unroll
    for (int j = 0; j < 4; j++) {
        #pragma unroll
        for (int reg = 0; reg < 4; reg++) {
            int t = 16 * w + lg * 4 + reg;
            int v = 16 * j + lr;
            ACC[t * D_SZ + (v ^ (((t >> 2) & 1) << 4))] = acc[j][reg];
        }
    }
    __syncthreads();                                   // B6

    // coalesced column-pass epilogue (bon in registers; r/g read here — any
    // earlier placement spills: allocator pins 64 arch-VGPRs w/ 32 accs live)
    #pragma unroll
    for (int j = 0; j < 16; j++) {
        int t = qq * 16 + j;
        size_t off = base + (size_t)t * STRIDE_T + col;
        float a = ACC[t * D_SZ + (col ^ (((t >> 2) & 1) << 4))];
        out[off] = rq[off] * (a + bon[j]) * gq[off];
    }
}

extern "C" void kernel_launch(void* const* d_in, const int* in_sizes, int n_in,
                              void* d_out, int out_size, void* d_ws, size_t ws_size,
                              hipStream_t stream) {
    const float* k    = (const float*)d_in[0];
    const float* v    = (const float*)d_in[1];
    const float* dt   = (const float*)d_in[2];
    const float* Bvec = (const float*)d_in[3];
    // d_in[4] = C_vec (unused by reference)
    const float* r    = (const float*)d_in[5];
    const float* g    = (const float*)d_in[6];
    const float* bd   = (const float*)d_in[7];
    const float* tf   = (const float*)d_in[8];

    float* out  = (float*)d_out;
    float* out2 = out + (size_t)B_SZ * L_SZ * H_SZ * D_SZ;

    float* Bs  = (float*)d_ws;                              // B*L fp32
    float* P   = Bs + B_SZ * L_SZ;                          // BH*C*D fp32
    ushort* Qb = (ushort*)(P + (size_t)BH * C_CH * D_SZ);   // BH*C*D*D bf16 (16.8 MB)

    bs_kernel<<<dim3(B_SZ * L_SZ / 4), 256, 0, stream>>>(Bvec, Bs);
    phase1_mfma<<<dim3(C_CH, BH), 256, 0, stream>>>(k, v, dt, Bs, bd, P, Qb);
    phase2<<<dim3(BH, 8), 64, 0, stream>>>(P, Qb, out2);
    phase3_mfma<<<dim3(C_CH, BH), 256, 0, stream>>>(k, v, dt, r, g, Bs, bd, tf, Qb, out);
}